// Round 5
// baseline (3275.914 us; speedup 1.0000x reference)
//
#include <hip/hip_runtime.h>
#include <hip/hip_bf16.h>

typedef __bf16 bf16_t;
typedef __bf16 bf16x8 __attribute__((ext_vector_type(8)));
typedef float f32x4 __attribute__((ext_vector_type(4)));

#define SEQLEN 256
#define NBATCH 64
#define INDIM  512
#define HID    1024
#define NGATE  4096
#define NBLK   128

// workspace layout (bytes)
#define XG_OFF   0ull                // bf16 [16384][4096]  = 134217728
#define XBF_OFF  134217728ull        // bf16 [16384][512]   = 16777216 (dead after gemm; fallback h-ring)
#define WX_OFF   150994944ull        // bf16 [4096][512]    = 4194304  (dead after gemm; ARR flags overlay, 2 MB)
#define WH_OFF   155189248ull        // bf16 [4096][1024]   = 8388608
#define BS_OFF   163577856ull        // f32  [4096]         = 16384
#define HSEQ_OFF 163594240ull        // bf16 [257][64][1024] = 33685504 (primary write-once h slots)
#define SLOT_ELEMS (NBATCH * HID)    // 65536 bf16 = 131072 B per slot
#define SLOT_BYTES 131072ull
#define PRIMARY_WS_NEED (HSEQ_OFF + 257ull * SLOT_BYTES)

__device__ __forceinline__ bf16x8 cvt8(float4 a, float4 b) {
  bf16x8 v;
  v[0] = (bf16_t)a.x; v[1] = (bf16_t)a.y; v[2] = (bf16_t)a.z; v[3] = (bf16_t)a.w;
  v[4] = (bf16_t)b.x; v[5] = (bf16_t)b.y; v[6] = (bf16_t)b.z; v[7] = (bf16_t)b.w;
  return v;
}

__device__ __forceinline__ float bfbits(unsigned int w, int hi) {
  unsigned int u = hi ? (w & 0xffff0000u) : (w << 16);
  return __builtin_bit_cast(float, u);
}

// ---------------- pack x -> bf16 ----------------
__global__ __launch_bounds__(256) void pack_x_k(const float* __restrict__ x,
                                                bf16_t* __restrict__ xb) {
  int idx = blockIdx.x * 256 + threadIdx.x;
  const float4* s = (const float4*)x + (size_t)idx * 2;
  float4 a = s[0], b = s[1];
  *(bf16x8*)(xb + (size_t)idx * 8) = cvt8(a, b);
}

// ---------------- pack weights (gate-permuted rows) + bias sums ----------------
struct GatePtrs {
  const float* Wi[4];
  const float* bi[4];
  const float* Wh[4];
  const float* bh[4];
};

__global__ __launch_bounds__(256) void pack_w_k(GatePtrs p,
                                                bf16_t* __restrict__ Wx,
                                                bf16_t* __restrict__ Wh,
                                                float* __restrict__ bsum) {
  int idx = blockIdx.x * 256 + threadIdx.x;       // 0 .. 786431
  int row = idx / 192;                            // n_packed, 0..4095
  int c   = idx % 192;
  int blk = row >> 5, r = row & 31, g = r >> 3, jj = r & 7;
  int j = blk * 8 + jj;
  if (c == 0) bsum[row] = p.bi[g][j] + p.bh[g][j];
  if (c < 64) {
    const float4* s = (const float4*)(p.Wi[g] + (size_t)j * INDIM + c * 8);
    *(bf16x8*)(Wx + (size_t)row * INDIM + c * 8) = cvt8(s[0], s[1]);
  } else {
    int cc = c - 64;
    const float4* s = (const float4*)(p.Wh[g] + (size_t)j * HID + cc * 8);
    *(bf16x8*)(Wh + (size_t)row * HID + cc * 8) = cvt8(s[0], s[1]);
  }
}

// ---------------- phase 1: xg = x @ Wx^T + bsum (bf16 out) ----------------
__global__ __launch_bounds__(256) void gemm_xproj_k(const bf16_t* __restrict__ A,
                                                    const bf16_t* __restrict__ B,
                                                    const float* __restrict__ bsum,
                                                    bf16_t* __restrict__ C) {
  __shared__ bf16_t As[128 * 32];
  __shared__ bf16_t Bs[128 * 32];
  const int tid = threadIdx.x, w = tid >> 6, l = tid & 63;
  const int m0 = blockIdx.y * 128, n0 = blockIdx.x * 128;
  const int wr = (w >> 1) * 64, wc = (w & 1) * 64;
  const int kg = (l >> 4) * 8, rr = l & 15;
  f32x4 acc[4][4] = {};

  const int segrow = l >> 2, segk = (l & 3) * 8;
  for (int k0 = 0; k0 < INDIM; k0 += 32) {
    __syncthreads();
#pragma unroll
    for (int i = 0; i < 2; ++i) {
      int seg = w * 2 + i;
      const bf16_t* ga = A + (size_t)(m0 + seg * 16 + segrow) * INDIM + k0 + segk;
      __builtin_amdgcn_global_load_lds((const __attribute__((address_space(1))) void*)ga,
                                       (__attribute__((address_space(3))) void*)(As + seg * 512),
                                       16, 0, 0);
      const bf16_t* gb = B + (size_t)(n0 + seg * 16 + segrow) * INDIM + k0 + segk;
      __builtin_amdgcn_global_load_lds((const __attribute__((address_space(1))) void*)gb,
                                       (__attribute__((address_space(3))) void*)(Bs + seg * 512),
                                       16, 0, 0);
    }
    __syncthreads();
    bf16x8 af[4], bfr[4];
#pragma unroll
    for (int mi = 0; mi < 4; ++mi) af[mi]  = *(const bf16x8*)(As + (wr + mi * 16 + rr) * 32 + kg);
#pragma unroll
    for (int ni = 0; ni < 4; ++ni) bfr[ni] = *(const bf16x8*)(Bs + (wc + ni * 16 + rr) * 32 + kg);
#pragma unroll
    for (int mi = 0; mi < 4; ++mi)
#pragma unroll
      for (int ni = 0; ni < 4; ++ni)
        acc[mi][ni] = __builtin_amdgcn_mfma_f32_16x16x32_bf16(af[mi], bfr[ni], acc[mi][ni], 0, 0, 0);
  }
  const int ri = (l >> 4) * 4;
#pragma unroll
  for (int ni = 0; ni < 4; ++ni) {
    int n = n0 + wc + ni * 16 + rr;
    float bs = bsum[n];
#pragma unroll
    for (int mi = 0; mi < 4; ++mi) {
      int mbase = m0 + wr + mi * 16 + ri;
#pragma unroll
      for (int r = 0; r < 4; ++r)
        C[(size_t)(mbase + r) * NGATE + n] = (bf16_t)(acc[mi][ni][r] + bs);
    }
  }
}

// ---------------- phase 2: persistent recurrence ----------------
// 128 blocks x 256 threads (4 waves). Block b owns gate-rows [b*32,+32) == h cols [b*8,+8).
// Wave w: batches [16w,+16) x 32 rows x FULL K=1024 -> acc is only 2 f32x4; no cross-wave
// reduction (deterministic). h(t) staged per-wave into a 32 KB LDS slab in MFMA-fragment
// order via 32x global_load_lds (DMA -> nothing to spill); one vmcnt(0) per step.
// Weight B-fragments re-read from global each step (64 KB/block, L2-resident).
template<int COHERENT>
__global__ __launch_bounds__(256, 1) void lstm_rec_k(const bf16_t* __restrict__ Wh,
                                                     const bf16_t* __restrict__ xg,
                                                     bf16_t* __restrict__ hseq,
                                                     float* __restrict__ out,
                                                     int* __restrict__ arr,
                                                     int R) {
  const int b = blockIdx.x;
  const int tid = threadIdx.x;
  const int w = tid >> 6, l = tid & 63;

  __shared__ bf16_t hslab[4][32][64][8];   // 128 KB: [wave][kk][lane][8] fragment-ordered
  __shared__ float  accbuf[4][32][20];     // 10 KB: [wave][gate-row][batch16+pad]

  // invariant lane offsets
  const int fr = l & 15, fk = (l >> 4) * 8;              // fragment row / k-offset
  const size_t hlane = (size_t)(16 * w + fr) * HID + fk; // into h slot
  const bf16_t* wp0 = Wh + ((size_t)b * 32 + fr) * HID + fk;
  const bf16_t* wp1 = wp0 + (size_t)16 * HID;

  // elementwise ownership: batch = 16w + (l>>2), cols jp, jp+1
  const int ebl = l >> 2, jp = (l & 3) * 2;
  const int ebatch = 16 * w + ebl;
  const int j0 = b * 8 + jp;
  float cs0 = 0.f, cs1 = 0.f;

  for (int t = 0; t < SEQLEN; ++t) {
    if (COHERENT) __builtin_amdgcn_fence(__ATOMIC_ACQUIRE, "agent");

    // xg gate dwords for this step (consumed after MFMA; latency rides under staging)
    const char* xb = (const char*)xg + (((size_t)t * NBATCH + ebatch) * NGATE + b * 32 + jp) * 2;
    unsigned int xw0 = *(const unsigned int*)(xb);
    unsigned int xw1 = *(const unsigned int*)(xb + 16);
    unsigned int xw2 = *(const unsigned int*)(xb + 32);
    unsigned int xw3 = *(const unsigned int*)(xb + 48);

    // stage h(t) -> wave-private fragment-ordered slab (32 x 1KB DMA)
    const bf16_t* hsrc = hseq + (size_t)(t % R) * SLOT_ELEMS + hlane;
#pragma unroll
    for (int kk = 0; kk < 32; ++kk)
      __builtin_amdgcn_global_load_lds((const __attribute__((address_space(1))) void*)(hsrc + kk * 32),
                                       (__attribute__((address_space(3))) void*)&hslab[w][kk][0][0],
                                       16, 0, 0);
    asm volatile("s_waitcnt vmcnt(0)" ::: "memory");
    __builtin_amdgcn_sched_barrier(0);

    // MFMA: full-K accumulate; B-frags from global (L2-hot), A-frags conflict-free ds_read
    f32x4 acc0 = {}, acc1 = {};
#pragma unroll
    for (int kk = 0; kk < 32; ++kk) {
      bf16x8 hf = *(const bf16x8*)&hslab[w][kk][l][0];
      bf16x8 w0 = *(const bf16x8*)(wp0 + kk * 32);
      bf16x8 w1 = *(const bf16x8*)(wp1 + kk * 32);
      acc0 = __builtin_amdgcn_mfma_f32_16x16x32_bf16(hf, w0, acc0, 0, 0, 0);
      acc1 = __builtin_amdgcn_mfma_f32_16x16x32_bf16(hf, w1, acc1, 0, 0, 0);
    }

    // transpose through wave-private LDS: acc (row=fr, batch=(l>>4)*4+r) -> accbuf
    *(f32x4*)&accbuf[w][fr][(l >> 4) * 4]      = acc0;
    *(f32x4*)&accbuf[w][16 + fr][(l >> 4) * 4] = acc1;
    // (same-wave ds ordering; no barrier needed)

    // fused elementwise: 2 cells per thread (cols jp, jp+1)
    float hv[2], cf[2];
#pragma unroll
    for (int q = 0; q < 2; ++q) {
      const int jj = jp + q;
      float pf = accbuf[w][jj][ebl]      + bfbits(xw0, q);
      float pi = accbuf[w][8 + jj][ebl]  + bfbits(xw1, q);
      float po = accbuf[w][16 + jj][ebl] + bfbits(xw2, q);
      float pc = accbuf[w][24 + jj][ebl] + bfbits(xw3, q);
      float fg = 1.f / (1.f + __expf(-pf));
      float ig = 1.f / (1.f + __expf(-pi));
      float og = 1.f / (1.f + __expf(-po));
      float e2 = __expf(-2.f * fabsf(pc));
      float gg = __builtin_copysignf((1.f - e2) / (1.f + e2), pc);
      float& cs = q ? cs1 : cs0;
      cs = fg * cs + ig * gg;
      float e2c = __expf(-2.f * fabsf(cs));
      float th = __builtin_copysignf((1.f - e2c) / (1.f + e2c), cs);
      hv[q] = og * th;
      cf[q] = cs;
    }
    *(float2*)(out + ((size_t)t * NBATCH + ebatch) * HID + j0) = make_float2(hv[0], hv[1]);
    // publish h(t+1): packed bf16 pair, write-through agent store
    unsigned int pk = (unsigned int)__builtin_bit_cast(unsigned short, (bf16_t)hv[0]) |
                      ((unsigned int)__builtin_bit_cast(unsigned short, (bf16_t)hv[1]) << 16);
    unsigned int* hd = (unsigned int*)(hseq + (size_t)((t + 1) % R) * SLOT_ELEMS) + ebatch * (HID / 2) + (j0 >> 1);
    __hip_atomic_store(hd, pk, __ATOMIC_RELAXED, __HIP_MEMORY_SCOPE_AGENT);
    if (t == SEQLEN - 1) {
      *(float2*)(out + (size_t)SEQLEN * NBATCH * HID + (size_t)ebatch * HID + j0) = make_float2(hv[0], hv[1]);
      *(float2*)(out + (size_t)SEQLEN * NBATCH * HID + (size_t)NBATCH * HID + (size_t)ebatch * HID + j0) = make_float2(cf[0], cf[1]);
    }

    // distributed grid barrier
    if (t < SEQLEN - 1) {
      __syncthreads();   // drains vmcnt: all h-stores performed at IC
      if (tid == 0)
        __hip_atomic_store(&arr[(t * NBLK + b) * 16], t + 1, __ATOMIC_RELAXED, __HIP_MEMORY_SCOPE_AGENT);
      if (tid >= 128) {
        const int blk = tid - 128;     // 128 pollers, one flag each
        while (__hip_atomic_load(&arr[(t * NBLK + blk) * 16], __ATOMIC_RELAXED, __HIP_MEMORY_SCOPE_AGENT) != t + 1)
          __builtin_amdgcn_s_sleep(1);
      }
      __syncthreads();
      __builtin_amdgcn_sched_barrier(0);
    }
  }
}

extern "C" void kernel_launch(void* const* d_in, const int* in_sizes, int n_in,
                              void* d_out, int out_size, void* d_ws, size_t ws_size,
                              hipStream_t stream) {
  (void)in_sizes; (void)n_in; (void)out_size;
  char* ws = (char*)d_ws;
  bf16_t* xg  = (bf16_t*)(ws + XG_OFF);
  bf16_t* xbf = (bf16_t*)(ws + XBF_OFF);
  bf16_t* Wx  = (bf16_t*)(ws + WX_OFF);
  bf16_t* Wh  = (bf16_t*)(ws + WH_OFF);
  float*  bs  = (float*)(ws + BS_OFF);
  int*    arr = (int*)(ws + WX_OFF);    // Wx dead after gemm; 2 MB flag array

  const float* x = (const float*)d_in[0];
  GatePtrs p;
  for (int g = 0; g < 4; ++g) {
    p.Wi[g] = (const float*)d_in[1 + 4 * g];
    p.bi[g] = (const float*)d_in[2 + 4 * g];
    p.Wh[g] = (const float*)d_in[3 + 4 * g];
    p.bh[g] = (const float*)d_in[4 + 4 * g];
  }

  const bool primary = ws_size >= PRIMARY_WS_NEED;
  bf16_t* hseq = primary ? (bf16_t*)(ws + HSEQ_OFF) : (bf16_t*)(ws + XBF_OFF);
  const int R  = primary ? 257 : 128;

  pack_x_k<<<4096, 256, 0, stream>>>(x, xbf);
  pack_w_k<<<3072, 256, 0, stream>>>(p, Wx, Wh, bs);
  gemm_xproj_k<<<dim3(32, 128), 256, 0, stream>>>(xbf, Wx, bs, xg);
  hipMemsetAsync(arr, 0, 256 * NBLK * 64, stream);
  hipMemsetAsync(hseq, 0, SLOT_BYTES, stream);
  if (primary)
    lstm_rec_k<0><<<NBLK, 256, 0, stream>>>(Wh, xg, hseq, (float*)d_out, arr, R);
  else
    lstm_rec_k<1><<<NBLK, 256, 0, stream>>>(Wh, xg, hseq, (float*)d_out, arr, R);
}

// Round 6
// 1383.630 us; speedup vs baseline: 2.3676x; 2.3676x over previous
//
#include <hip/hip_runtime.h>
#include <hip/hip_bf16.h>

typedef __bf16 bf16_t;
typedef __bf16 bf16x8 __attribute__((ext_vector_type(8)));
typedef float f32x4 __attribute__((ext_vector_type(4)));

#define SEQLEN 256
#define NBATCH 64
#define INDIM  512
#define HID    1024
#define NGATE  4096
#define NBLK   128

// workspace layout (bytes)
#define XG_OFF   0ull                // bf16 [16384][4096]  = 134217728
#define XBF_OFF  134217728ull        // bf16 [16384][512]   = 16777216 (dead after gemm; fallback h-ring)
#define WX_OFF   150994944ull        // bf16 [4096][512]    = 4194304  (dead after gemm; ARR flags overlay, 2 MB)
#define WF_OFF   155189248ull        // bf16 [128 blk][32768] = 8388608 (fragment-ordered W_h)
#define BS_OFF   163577856ull        // f32  [4096]         = 16384
#define HSEQ_OFF 163594240ull        // bf16 [257][64][1024] = 33685504 (write-once fragment-ordered h slots)
#define SLOT_ELEMS (NBATCH * HID)    // 65536 bf16 = 131072 B per slot
#define SLOT_BYTES 131072ull
#define PRIMARY_WS_NEED (HSEQ_OFF + 257ull * SLOT_BYTES)

__device__ __forceinline__ bf16x8 cvt8(float4 a, float4 b) {
  bf16x8 v;
  v[0] = (bf16_t)a.x; v[1] = (bf16_t)a.y; v[2] = (bf16_t)a.z; v[3] = (bf16_t)a.w;
  v[4] = (bf16_t)b.x; v[5] = (bf16_t)b.y; v[6] = (bf16_t)b.z; v[7] = (bf16_t)b.w;
  return v;
}

__device__ __forceinline__ float bfbits(unsigned int w, int hi) {
  unsigned int u = hi ? (w & 0xffff0000u) : (w << 16);
  return __builtin_bit_cast(float, u);
}

// ---------------- pack x -> bf16 ----------------
__global__ __launch_bounds__(256) void pack_x_k(const float* __restrict__ x,
                                                bf16_t* __restrict__ xb) {
  int idx = blockIdx.x * 256 + threadIdx.x;
  const float4* s = (const float4*)x + (size_t)idx * 2;
  float4 a = s[0], b = s[1];
  *(bf16x8*)(xb + (size_t)idx * 8) = cvt8(a, b);
}

// ---------------- pack weights + bias sums ----------------
// Wx: row-major packed rows (GEMM B operand). Wf: MFMA-fragment order per recurrence block:
//   elem(block, kk, g2, l, e): row g2*16+(l&15) of block's 32 packed rows, col kk*32+(l>>4)*8+e.
struct GatePtrs {
  const float* Wi[4];
  const float* bi[4];
  const float* Wh[4];
  const float* bh[4];
};

__global__ __launch_bounds__(256) void pack_w_k(GatePtrs p,
                                                bf16_t* __restrict__ Wx,
                                                bf16_t* __restrict__ Wf,
                                                float* __restrict__ bsum) {
  int idx = blockIdx.x * 256 + threadIdx.x;       // 0 .. 786431
  int row = idx / 192;                            // n_packed, 0..4095
  int c   = idx % 192;
  int blk = row >> 5, r32 = row & 31, g = r32 >> 3, jj = r32 & 7;
  int j = blk * 8 + jj;                           // original hidden index
  if (c == 0) bsum[row] = p.bi[g][j] + p.bh[g][j];
  if (c < 64) {
    const float4* s = (const float4*)(p.Wi[g] + (size_t)j * INDIM + c * 8);
    *(bf16x8*)(Wx + (size_t)row * INDIM + c * 8) = cvt8(s[0], s[1]);
  } else {
    int cc = c - 64;                              // 8-col chunk 0..127 of W_h row j
    const float4* s = (const float4*)(p.Wh[g] + (size_t)j * HID + cc * 8);
    int g2 = r32 >> 4, lrow = r32 & 15;
    int kk = cc >> 2, sub = cc & 3, l = lrow + 16 * sub;
    *(bf16x8*)(Wf + (size_t)blk * 32768 + ((kk * 2 + g2) * 64 + l) * 8) = cvt8(s[0], s[1]);
  }
}

// ---------------- phase 1: xg = x @ Wx^T + bsum (bf16 out) ----------------
__global__ __launch_bounds__(256) void gemm_xproj_k(const bf16_t* __restrict__ A,
                                                    const bf16_t* __restrict__ B,
                                                    const float* __restrict__ bsum,
                                                    bf16_t* __restrict__ C) {
  __shared__ bf16_t As[128 * 32];
  __shared__ bf16_t Bs[128 * 32];
  const int tid = threadIdx.x, w = tid >> 6, l = tid & 63;
  const int m0 = blockIdx.y * 128, n0 = blockIdx.x * 128;
  const int wr = (w >> 1) * 64, wc = (w & 1) * 64;
  const int kg = (l >> 4) * 8, rr = l & 15;
  f32x4 acc[4][4] = {};

  const int segrow = l >> 2, segk = (l & 3) * 8;
  for (int k0 = 0; k0 < INDIM; k0 += 32) {
    __syncthreads();
#pragma unroll
    for (int i = 0; i < 2; ++i) {
      int seg = w * 2 + i;
      const bf16_t* ga = A + (size_t)(m0 + seg * 16 + segrow) * INDIM + k0 + segk;
      __builtin_amdgcn_global_load_lds((const __attribute__((address_space(1))) void*)ga,
                                       (__attribute__((address_space(3))) void*)(As + seg * 512),
                                       16, 0, 0);
      const bf16_t* gb = B + (size_t)(n0 + seg * 16 + segrow) * INDIM + k0 + segk;
      __builtin_amdgcn_global_load_lds((const __attribute__((address_space(1))) void*)gb,
                                       (__attribute__((address_space(3))) void*)(Bs + seg * 512),
                                       16, 0, 0);
    }
    __syncthreads();
    bf16x8 af[4], bfr[4];
#pragma unroll
    for (int mi = 0; mi < 4; ++mi) af[mi]  = *(const bf16x8*)(As + (wr + mi * 16 + rr) * 32 + kg);
#pragma unroll
    for (int ni = 0; ni < 4; ++ni) bfr[ni] = *(const bf16x8*)(Bs + (wc + ni * 16 + rr) * 32 + kg);
#pragma unroll
    for (int mi = 0; mi < 4; ++mi)
#pragma unroll
      for (int ni = 0; ni < 4; ++ni)
        acc[mi][ni] = __builtin_amdgcn_mfma_f32_16x16x32_bf16(af[mi], bfr[ni], acc[mi][ni], 0, 0, 0);
  }
  const int ri = (l >> 4) * 4;
#pragma unroll
  for (int ni = 0; ni < 4; ++ni) {
    int n = n0 + wc + ni * 16 + rr;
    float bs = bsum[n];
#pragma unroll
    for (int mi = 0; mi < 4; ++mi) {
      int mbase = m0 + wr + mi * 16 + ri;
#pragma unroll
      for (int r = 0; r < 4; ++r)
        C[(size_t)(mbase + r) * NGATE + n] = (bf16_t)(acc[mi][ni][r] + bs);
    }
  }
}

// ---------------- phase 2: persistent recurrence ----------------
// 128 blocks x 512 threads (8 waves). Block b owns gate-rows [b*32,+32) == h cols [b*8,+8).
// Wave w: bg = w>>1 (batches 16bg..+16), kh = w&1 (K half). h slots are stored in MFMA
// fragment order -> staging = 16x fully-coalesced 1KB global_load_lds per wave (one vmcnt);
// weights in fragment order -> 16B/lane coalesced L2-resident loads per MFMA. K-partials
// (2 per cell) reduced through LDS in the elementwise pass. No fences (write-once slots).
template<int COHERENT>
__global__ __launch_bounds__(512, 1) void lstm_rec_k(const bf16_t* __restrict__ Wf,
                                                     const bf16_t* __restrict__ xg,
                                                     bf16_t* __restrict__ hseq,
                                                     float* __restrict__ out,
                                                     int* __restrict__ arr,
                                                     int R) {
  const int b = blockIdx.x;
  const int tid = threadIdx.x;
  const int w = tid >> 6, l = tid & 63;
  const int bg = w >> 1, kh = w & 1;

  __shared__ bf16_t hslab[8][16][64 * 8];   // 128 KB, [wave][kkl][lane*8], fragment-ordered
  __shared__ float  accbuf[2][32][68];      // 17 KB,  [kh][gate-row][batch64+pad]

  const bf16_t* wfb = Wf + (size_t)b * 32768;

  // elementwise ownership (threads 0..255): batch = tid>>2, cols jp, jp+1
  const int ebatch = tid >> 2, jp = (tid & 3) * 2;
  const int j0 = b * 8 + jp;
  // publish address components (fragment order): e = jp, kkp = b>>2, sub = b&3
  const int lp = (ebatch & 15) + 16 * (b & 3);
  const int wv = ebatch >> 4;
  const size_t pub_off = (size_t)(((b >> 2) * 4 + wv) * 64 + lp) * 16 + jp * 2;  // bytes
  float cs0 = 0.f, cs1 = 0.f;

  for (int t = 0; t < SEQLEN; ++t) {
    if (COHERENT) __builtin_amdgcn_fence(__ATOMIC_ACQUIRE, "agent");

    // xg gate dwords (threads 0..255), in flight across staging
    unsigned int xw0, xw1, xw2, xw3;
    if (tid < 256) {
      const char* xb = (const char*)xg + (((size_t)t * NBATCH + ebatch) * NGATE + b * 32 + jp) * 2;
      xw0 = *(const unsigned int*)(xb);
      xw1 = *(const unsigned int*)(xb + 16);
      xw2 = *(const unsigned int*)(xb + 32);
      xw3 = *(const unsigned int*)(xb + 48);
    }

    // ---- stage h(t): 16 x 1KB coalesced DMA per wave, one latency exposure ----
    const char* slot = (const char*)hseq + (size_t)(t % R) * SLOT_BYTES;
#pragma unroll
    for (int kkl = 0; kkl < 16; ++kkl) {
      const int kkg = kh * 16 + kkl;
      const char* src = slot + ((size_t)((kkg * 4 + bg) * 64 + l)) * 16;
      __builtin_amdgcn_global_load_lds((const __attribute__((address_space(1))) void*)src,
                                       (__attribute__((address_space(3))) void*)&hslab[w][kkl][0],
                                       16, 0, 0);
    }
    asm volatile("s_waitcnt vmcnt(0)" ::: "memory");
    __builtin_amdgcn_sched_barrier(0);

    // ---- MFMA: 16 iters, A from LDS, B coalesced from L2 ----
    f32x4 acc0 = {}, acc1 = {};
#pragma unroll
    for (int kkl = 0; kkl < 16; ++kkl) {
      const int kkg = kh * 16 + kkl;
      bf16x8 hf = *(const bf16x8*)&hslab[w][kkl][l * 8];
      bf16x8 w0 = *(const bf16x8*)(wfb + ((kkg * 2 + 0) * 64 + l) * 8);
      bf16x8 w1 = *(const bf16x8*)(wfb + ((kkg * 2 + 1) * 64 + l) * 8);
      acc0 = __builtin_amdgcn_mfma_f32_16x16x32_bf16(hf, w0, acc0, 0, 0, 0);
      acc1 = __builtin_amdgcn_mfma_f32_16x16x32_bf16(hf, w1, acc1, 0, 0, 0);
    }

    // D layout: batch16 = (l>>4)*4 + reg, gate-row = g2*16 + (l&15)
    *(f32x4*)&accbuf[kh][l & 15][bg * 16 + (l >> 4) * 4]        = acc0;
    *(f32x4*)&accbuf[kh][16 + (l & 15)][bg * 16 + (l >> 4) * 4] = acc1;
    __syncthreads();

    // ---- fused elementwise (threads 0..255, 2 cells each) ----
    if (tid < 256) {
      float hv[2], cf[2];
#pragma unroll
      for (int q = 0; q < 2; ++q) {
        const int jj = jp + q;
        float pf = bfbits(xw0, q) + accbuf[0][jj][ebatch]      + accbuf[1][jj][ebatch];
        float pi = bfbits(xw1, q) + accbuf[0][8 + jj][ebatch]  + accbuf[1][8 + jj][ebatch];
        float po = bfbits(xw2, q) + accbuf[0][16 + jj][ebatch] + accbuf[1][16 + jj][ebatch];
        float pc = bfbits(xw3, q) + accbuf[0][24 + jj][ebatch] + accbuf[1][24 + jj][ebatch];
        float fg = 1.f / (1.f + __expf(-pf));
        float ig = 1.f / (1.f + __expf(-pi));
        float og = 1.f / (1.f + __expf(-po));
        float e2 = __expf(-2.f * fabsf(pc));
        float gg = __builtin_copysignf((1.f - e2) / (1.f + e2), pc);
        float& cs = q ? cs1 : cs0;
        cs = fg * cs + ig * gg;
        float e2c = __expf(-2.f * fabsf(cs));
        float th = __builtin_copysignf((1.f - e2c) / (1.f + e2c), cs);
        hv[q] = og * th;
        cf[q] = cs;
      }
      *(float2*)(out + ((size_t)t * NBATCH + ebatch) * HID + j0) = make_float2(hv[0], hv[1]);
      // publish h(t+1) in fragment order: packed bf16 pair, write-through agent store
      unsigned int pk = (unsigned int)__builtin_bit_cast(unsigned short, (bf16_t)hv[0]) |
                        ((unsigned int)__builtin_bit_cast(unsigned short, (bf16_t)hv[1]) << 16);
      unsigned int* hd = (unsigned int*)((char*)hseq + (size_t)((t + 1) % R) * SLOT_BYTES + pub_off);
      __hip_atomic_store(hd, pk, __ATOMIC_RELAXED, __HIP_MEMORY_SCOPE_AGENT);
      if (t == SEQLEN - 1) {
        *(float2*)(out + (size_t)SEQLEN * NBATCH * HID + (size_t)ebatch * HID + j0) = make_float2(hv[0], hv[1]);
        *(float2*)(out + (size_t)SEQLEN * NBATCH * HID + (size_t)NBATCH * HID + (size_t)ebatch * HID + j0) = make_float2(cf[0], cf[1]);
      }
    }

    // ---- distributed grid barrier ----
    if (t < SEQLEN - 1) {
      __syncthreads();   // drains vmcnt: all h-stores performed at IC
      if (tid == 0)
        __hip_atomic_store(&arr[(t * NBLK + b) * 16], t + 1, __ATOMIC_RELAXED, __HIP_MEMORY_SCOPE_AGENT);
      if (tid >= 384) {
        const int blk = tid - 384;     // 128 pollers, one flag each
        while (__hip_atomic_load(&arr[(t * NBLK + blk) * 16], __ATOMIC_RELAXED, __HIP_MEMORY_SCOPE_AGENT) != t + 1)
          __builtin_amdgcn_s_sleep(1);
      }
      __syncthreads();
      __builtin_amdgcn_sched_barrier(0);
    }
  }
}

extern "C" void kernel_launch(void* const* d_in, const int* in_sizes, int n_in,
                              void* d_out, int out_size, void* d_ws, size_t ws_size,
                              hipStream_t stream) {
  (void)in_sizes; (void)n_in; (void)out_size;
  char* ws = (char*)d_ws;
  bf16_t* xg  = (bf16_t*)(ws + XG_OFF);
  bf16_t* xbf = (bf16_t*)(ws + XBF_OFF);
  bf16_t* Wx  = (bf16_t*)(ws + WX_OFF);
  bf16_t* Wf  = (bf16_t*)(ws + WF_OFF);
  float*  bs  = (float*)(ws + BS_OFF);
  int*    arr = (int*)(ws + WX_OFF);    // Wx dead after gemm; 2 MB flag array

  const float* x = (const float*)d_in[0];
  GatePtrs p;
  for (int g = 0; g < 4; ++g) {
    p.Wi[g] = (const float*)d_in[1 + 4 * g];
    p.bi[g] = (const float*)d_in[2 + 4 * g];
    p.Wh[g] = (const float*)d_in[3 + 4 * g];
    p.bh[g] = (const float*)d_in[4 + 4 * g];
  }

  const bool primary = ws_size >= PRIMARY_WS_NEED;
  bf16_t* hseq = primary ? (bf16_t*)(ws + HSEQ_OFF) : (bf16_t*)(ws + XBF_OFF);
  const int R  = primary ? 257 : 128;

  pack_x_k<<<4096, 256, 0, stream>>>(x, xbf);
  pack_w_k<<<3072, 256, 0, stream>>>(p, Wx, Wf, bs);
  gemm_xproj_k<<<dim3(32, 128), 256, 0, stream>>>(xbf, Wx, bs, xg);
  hipMemsetAsync(arr, 0, 256 * NBLK * 64, stream);
  hipMemsetAsync(hseq, 0, SLOT_BYTES, stream);
  if (primary)
    lstm_rec_k<0><<<NBLK, 512, 0, stream>>>(Wf, xg, hseq, (float*)d_out, arr, R);
  else
    lstm_rec_k<1><<<NBLK, 512, 0, stream>>>(Wf, xg, hseq, (float*)d_out, arr, R);
}

// Round 7
// 1065.125 us; speedup vs baseline: 3.0756x; 1.2990x over previous
//
#include <hip/hip_runtime.h>
#include <hip/hip_bf16.h>

typedef __bf16 bf16_t;
typedef __bf16 bf16x8 __attribute__((ext_vector_type(8)));
typedef float f32x4 __attribute__((ext_vector_type(4)));
typedef int   i32x4 __attribute__((ext_vector_type(4)));

#define SEQLEN 256
#define NBATCH 64
#define INDIM  512
#define HID    1024
#define NBLK   128

// workspace layout (bytes) — total ~63 MB (well under the >=164 MB proven in R1)
#define XF_OFF   0ull            // bf16 [256][32768]  = 16777216  (x fragments, per-step 64 KB)
#define WXF_OFF  16777216ull     // bf16 [128][16384]  = 4194304   (W_i fragments per block)
#define WHF_OFF  20971520ull     // bf16 [128][32768]  = 8388608   (W_h fragments per block)
#define BS_OFF   29360128ull     // f32  [4096]        = 16384     (bias sums, packed-row order)
#define HSEQ_OFF 29376512ull     // bf16 [257][65536]  = 33685504  (write-once h slots, poisoned)
#define SLOT_BYTES 131072ull

__device__ __forceinline__ bf16x8 cvt8(float4 a, float4 b) {
  bf16x8 v;
  v[0] = (bf16_t)a.x; v[1] = (bf16_t)a.y; v[2] = (bf16_t)a.z; v[3] = (bf16_t)a.w;
  v[4] = (bf16_t)b.x; v[5] = (bf16_t)b.y; v[6] = (bf16_t)b.z; v[7] = (bf16_t)b.w;
  return v;
}

// ---------------- pack x -> bf16 MFMA A-fragment order ----------------
// xf elem(t, bg, kh, kkl, lane, e) = x[t][batch=bg*16+(lane&15)][k=(kh*8+kkl)*32+(lane>>4)*8+e]
__global__ __launch_bounds__(256) void pack_xf_k(const float* __restrict__ x,
                                                 bf16_t* __restrict__ xf) {
  int idx = blockIdx.x * 256 + threadIdx.x;     // 1,048,576 chunks of 8
  int t = idx >> 12;
  int r = idx & 4095;
  int batch = r >> 6, c8 = r & 63;
  const float4* s = (const float4*)(x + ((size_t)t * NBATCH + batch) * INDIM + c8 * 8);
  int kk = c8 >> 2, lhi = c8 & 3;
  int kh = kk >> 3, kkl = kk & 7;
  int bg = batch >> 4, lane = (batch & 15) + 16 * lhi;
  bf16_t* d = xf + (size_t)t * 32768 + (size_t)(((bg * 2 + kh) * 8 + kkl) * 64 + lane) * 8;
  *(bf16x8*)d = cvt8(s[0], s[1]);
}

// ---------------- pack weights (B-fragment order) + bias sums ----------------
struct GatePtrs {
  const float* Wi[4];
  const float* bi[4];
  const float* Wh[4];
  const float* bh[4];
};

__global__ __launch_bounds__(256) void pack_w_k(GatePtrs p,
                                                bf16_t* __restrict__ Wxf,
                                                bf16_t* __restrict__ Whf,
                                                float* __restrict__ bsum) {
  int idx = blockIdx.x * 256 + threadIdx.x;       // 0 .. 786431
  int row = idx / 192;                            // packed row, 0..4095
  int c   = idx % 192;
  int blk = row >> 5, r32 = row & 31, g = r32 >> 3, jj = r32 & 7;
  int j = blk * 8 + jj;                           // original hidden index
  int g2 = r32 >> 4, lrow = r32 & 15;
  if (c == 0) bsum[row] = p.bi[g][j] + p.bh[g][j];
  if (c < 64) {                                   // W_i row j, k-chunk c
    const float4* s = (const float4*)(p.Wi[g] + (size_t)j * INDIM + c * 8);
    int kk = c >> 2, lane = lrow + 16 * (c & 3);
    *(bf16x8*)(Wxf + (size_t)blk * 16384 + (size_t)((kk * 2 + g2) * 64 + lane) * 8) = cvt8(s[0], s[1]);
  } else {                                        // W_h row j, k-chunk cc
    int cc = c - 64;
    const float4* s = (const float4*)(p.Wh[g] + (size_t)j * HID + cc * 8);
    int kk = cc >> 2, lane = lrow + 16 * (cc & 3);
    *(bf16x8*)(Whf + (size_t)blk * 32768 + (size_t)((kk * 2 + g2) * 64 + lane) * 8) = cvt8(s[0], s[1]);
  }
}

// forced coherence-point loads for the data-flow poll (bypass L1/L2, pipelined issue)
#define PLD(dst, ptr, OFF) \
  asm volatile("global_load_dwordx4 %0, %1, off offset:" OFF " sc0 sc1" : "=v"(dst) : "v"(ptr))

// ---------------- persistent dataflow recurrence (no grid barrier) ----------------
// 128 blocks x 512 threads. Block b owns gate-rows [b*32,+32) == h cols [b*8,+8).
// Wave w: bg = w>>1 (batches 16bg..+16), kh = w&1 (K half). Slots write-once, poisoned
// 0xFFFFFFFF (bf16 NaN pair, unproducible); consumers poll their exact A-fragments at the
// coherence point until non-poison. K = 1024 (h, polled) + 512 (x, plain loads).
// Weights live in LDS (96 KB, preloaded once).
__global__ __launch_bounds__(512, 1) void lstm_rec_k(const bf16_t* __restrict__ Whf,
                                                     const bf16_t* __restrict__ Wxf,
                                                     const bf16_t* __restrict__ xf,
                                                     const float* __restrict__ bsum,
                                                     bf16_t* __restrict__ hseq,
                                                     float* __restrict__ out) {
  const int b = blockIdx.x;
  const int tid = threadIdx.x;
  const int w = tid >> 6, l = tid & 63;
  const int bg = w >> 1, kh = w & 1;

  __shared__ bf16_t wlds[49152];        // 96 KB: [0,32768) = Whf slice, [32768,49152) = Wxf slice
  __shared__ float  accbuf[2][32][68];  // 17 KB: [kh][gate-row][batch64+pad]

  // --- preload this block's weight fragments into LDS (coalesced DMA) ---
  {
    const bf16_t* whb = Whf + (size_t)b * 32768;
    const bf16_t* wxb = Wxf + (size_t)b * 16384;
#pragma unroll
    for (int i = 0; i < 8; ++i)
      __builtin_amdgcn_global_load_lds((const __attribute__((address_space(1))) void*)(whb + (i * 512 + tid) * 8),
                                       (__attribute__((address_space(3))) void*)(wlds + (i * 512 + tid) * 8),
                                       16, 0, 0);
#pragma unroll
    for (int i = 0; i < 4; ++i)
      __builtin_amdgcn_global_load_lds((const __attribute__((address_space(1))) void*)(wxb + (i * 512 + tid) * 8),
                                       (__attribute__((address_space(3))) void*)(wlds + 32768 + (i * 512 + tid) * 8),
                                       16, 0, 0);
  }

  // elementwise ownership (tid<256): batch = tid>>2, cols j0, j0+1
  const int ebatch = tid >> 2, jp = (tid & 3) * 2;
  const int j0 = b * 8 + jp;
  // publish byte offset inside a slot (fragment order)
  const int p_bg = ebatch >> 4, p_lrow = ebatch & 15;
  const int p_kkg = j0 >> 5, p_kh = p_kkg >> 4, p_kkl = p_kkg & 15;
  const int p_lane = p_lrow + 16 * ((j0 & 31) >> 3);
  const size_t pub_off = (size_t)((((p_bg * 2 + p_kh) * 16 + p_kkl) * 64 + p_lane)) * 16 + (j0 & 7) * 2;
  // biases (packed-row order) into regs
  float bsF[2], bsI[2], bsO[2], bsC[2];
  {
    const float* bp = bsum + b * 32;
    bsF[0] = bp[jp];      bsF[1] = bp[jp + 1];
    bsI[0] = bp[8 + jp];  bsI[1] = bp[8 + jp + 1];
    bsO[0] = bp[16 + jp]; bsO[1] = bp[16 + jp + 1];
    bsC[0] = bp[24 + jp]; bsC[1] = bp[24 + jp + 1];
  }
  float cs0 = 0.f, cs1 = 0.f;

  // wave-invariant poll base: fragment (bg,kh,kkl,l) at ((bg*2+kh)*16+kkl)*1024 + l*16 bytes
  const size_t pollbase = (size_t)((bg * 2 + kh) * 16) * 1024 + (size_t)l * 16;

  __syncthreads();   // weight LDS ready (barrier drains vmcnt incl. global_load_lds)

  for (int t = 0; t < SEQLEN; ++t) {
    // x fragments for this step: 8 plain coalesced loads (L3/L2 stream, hidden under poll)
    bf16x8 xv[8];
    {
      const bf16_t* xft = xf + (size_t)t * 32768 + (size_t)((bg * 2 + kh) * 8 * 64 + l) * 8;
#pragma unroll
      for (int i = 0; i < 8; ++i) xv[i] = *(const bf16x8*)(xft + i * 512);
    }

    // ---- data-flow poll: 16 in-flight coherent loads, per-dword poison check, retry ----
    const char* slot = (const char*)hseq + (size_t)t * SLOT_BYTES;
    const char* q0 = slot + pollbase;
    const char* q1 = q0 + 4096;
    const char* q2 = q0 + 8192;
    const char* q3 = q0 + 12288;
    i32x4 hv[16];
    for (;;) {
      PLD(hv[0],  q0, "0"); PLD(hv[1],  q0, "1024"); PLD(hv[2],  q0, "2048"); PLD(hv[3],  q0, "3072");
      PLD(hv[4],  q1, "0"); PLD(hv[5],  q1, "1024"); PLD(hv[6],  q1, "2048"); PLD(hv[7],  q1, "3072");
      PLD(hv[8],  q2, "0"); PLD(hv[9],  q2, "1024"); PLD(hv[10], q2, "2048"); PLD(hv[11], q2, "3072");
      PLD(hv[12], q3, "0"); PLD(hv[13], q3, "1024"); PLD(hv[14], q3, "2048"); PLD(hv[15], q3, "3072");
      asm volatile("s_waitcnt vmcnt(0)" ::: "memory");
      __builtin_amdgcn_sched_barrier(0);
      int bad = 0;
#pragma unroll
      for (int i = 0; i < 16; ++i) {
        bad |= (hv[i][0] == -1); bad |= (hv[i][1] == -1);
        bad |= (hv[i][2] == -1); bad |= (hv[i][3] == -1);
      }
      if (!__any(bad)) break;
      __builtin_amdgcn_s_sleep(2);
    }

    // ---- MFMA: h part (K=1024, from poll regs) + x part (K=512), B from LDS ----
    f32x4 acc0 = {}, acc1 = {};
#pragma unroll
    for (int kkl = 0; kkl < 16; ++kkl) {
      const int kk = kh * 16 + kkl;
      bf16x8 hf = __builtin_bit_cast(bf16x8, hv[kkl]);
      bf16x8 w0 = *(const bf16x8*)(wlds + (size_t)((kk * 2 + 0) * 64 + l) * 8);
      bf16x8 w1 = *(const bf16x8*)(wlds + (size_t)((kk * 2 + 1) * 64 + l) * 8);
      acc0 = __builtin_amdgcn_mfma_f32_16x16x32_bf16(hf, w0, acc0, 0, 0, 0);
      acc1 = __builtin_amdgcn_mfma_f32_16x16x32_bf16(hf, w1, acc1, 0, 0, 0);
    }
#pragma unroll
    for (int kkl = 0; kkl < 8; ++kkl) {
      const int kk = kh * 8 + kkl;
      bf16x8 w0 = *(const bf16x8*)(wlds + 32768 + (size_t)((kk * 2 + 0) * 64 + l) * 8);
      bf16x8 w1 = *(const bf16x8*)(wlds + 32768 + (size_t)((kk * 2 + 1) * 64 + l) * 8);
      acc0 = __builtin_amdgcn_mfma_f32_16x16x32_bf16(xv[kkl], w0, acc0, 0, 0, 0);
      acc1 = __builtin_amdgcn_mfma_f32_16x16x32_bf16(xv[kkl], w1, acc1, 0, 0, 0);
    }

    // D layout: gate-row = g2*16+(l&15), batch = bg*16+(l>>4)*4+reg
    *(f32x4*)&accbuf[kh][l & 15][bg * 16 + (l >> 4) * 4]        = acc0;
    *(f32x4*)&accbuf[kh][16 + (l & 15)][bg * 16 + (l >> 4) * 4] = acc1;
    __syncthreads();

    // ---- fused elementwise (tid<256; 2 cells each) ----
    if (tid < 256) {
      float hvv[2], cf[2];
#pragma unroll
      for (int q = 0; q < 2; ++q) {
        const int jj = jp + q;
        float pf = bsF[q] + accbuf[0][jj][ebatch]      + accbuf[1][jj][ebatch];
        float pi = bsI[q] + accbuf[0][8 + jj][ebatch]  + accbuf[1][8 + jj][ebatch];
        float po = bsO[q] + accbuf[0][16 + jj][ebatch] + accbuf[1][16 + jj][ebatch];
        float pc = bsC[q] + accbuf[0][24 + jj][ebatch] + accbuf[1][24 + jj][ebatch];
        float fg = 1.f / (1.f + __expf(-pf));
        float ig = 1.f / (1.f + __expf(-pi));
        float og = 1.f / (1.f + __expf(-po));
        float e2 = __expf(-2.f * fabsf(pc));
        float gg = __builtin_copysignf((1.f - e2) / (1.f + e2), pc);
        float& cs = q ? cs1 : cs0;
        cs = fg * cs + ig * gg;
        float e2c = __expf(-2.f * fabsf(cs));
        float th = __builtin_copysignf((1.f - e2c) / (1.f + e2c), cs);
        hvv[q] = og * th;
        cf[q] = cs;
      }
      *(float2*)(out + ((size_t)t * NBATCH + ebatch) * HID + j0) = make_float2(hvv[0], hvv[1]);
      // publish h(t+1): packed finite bf16 pair -> never equals poison
      unsigned int pk = (unsigned int)__builtin_bit_cast(unsigned short, (bf16_t)hvv[0]) |
                        ((unsigned int)__builtin_bit_cast(unsigned short, (bf16_t)hvv[1]) << 16);
      unsigned int* hd = (unsigned int*)((char*)hseq + (size_t)(t + 1) * SLOT_BYTES + pub_off);
      __hip_atomic_store(hd, pk, __ATOMIC_RELAXED, __HIP_MEMORY_SCOPE_AGENT);
      if (t == SEQLEN - 1) {
        *(float2*)(out + (size_t)SEQLEN * NBATCH * HID + (size_t)ebatch * HID + j0) = make_float2(hvv[0], hvv[1]);
        *(float2*)(out + (size_t)SEQLEN * NBATCH * HID + (size_t)NBATCH * HID + (size_t)ebatch * HID + j0) = make_float2(cf[0], cf[1]);
      }
    }
    __syncthreads();   // protect accbuf (next step's writes vs this step's reads)
  }
}

extern "C" void kernel_launch(void* const* d_in, const int* in_sizes, int n_in,
                              void* d_out, int out_size, void* d_ws, size_t ws_size,
                              hipStream_t stream) {
  (void)in_sizes; (void)n_in; (void)out_size; (void)ws_size;
  char* ws = (char*)d_ws;
  bf16_t* xf   = (bf16_t*)(ws + XF_OFF);
  bf16_t* Wxf  = (bf16_t*)(ws + WXF_OFF);
  bf16_t* Whf  = (bf16_t*)(ws + WHF_OFF);
  float*  bs   = (float*)(ws + BS_OFF);
  bf16_t* hseq = (bf16_t*)(ws + HSEQ_OFF);

  const float* x = (const float*)d_in[0];
  GatePtrs p;
  for (int g = 0; g < 4; ++g) {
    p.Wi[g] = (const float*)d_in[1 + 4 * g];
    p.bi[g] = (const float*)d_in[2 + 4 * g];
    p.Wh[g] = (const float*)d_in[3 + 4 * g];
    p.bh[g] = (const float*)d_in[4 + 4 * g];
  }

  pack_xf_k<<<4096, 256, 0, stream>>>(x, xf);
  pack_w_k<<<3072, 256, 0, stream>>>(p, Wxf, Whf, bs);
  // poison slots 1..256 (0xFF bytes = bf16 NaN pairs), zero slot 0 (= h(0))
  hipMemsetAsync((char*)hseq + SLOT_BYTES, 0xFF, 256ull * SLOT_BYTES, stream);
  hipMemsetAsync(hseq, 0, SLOT_BYTES, stream);
  lstm_rec_k<<<NBLK, 512, 0, stream>>>(Whf, Wxf, xf, bs, hseq, (float*)d_out);
}

// Round 8
// 861.872 us; speedup vs baseline: 3.8009x; 1.2358x over previous
//
#include <hip/hip_runtime.h>
#include <hip/hip_bf16.h>

typedef __bf16 bf16_t;
typedef __bf16 bf16x8 __attribute__((ext_vector_type(8)));
typedef float f32x4 __attribute__((ext_vector_type(4)));
typedef int   i32x4 __attribute__((ext_vector_type(4)));

#define SEQLEN 256
#define NBATCH 64
#define INDIM  512
#define HID    1024
#define NBLK   256

// workspace layout (bytes) — total ~63.3 MB
#define XF_OFF   0ull            // bf16 [256][32768]  = 16777216  (x fragments)
#define WXF_OFF  16777216ull     // bf16 [128][16384]  = 4194304   (W_i fragments per col-block)
#define WHF_OFF  20971520ull     // bf16 [128][32768]  = 8388608   (W_h fragments per col-block)
#define BS_OFF   29360128ull     // f32  [4096]        = 16384     (bias sums, packed-row order)
#define HSEQ_OFF 29376512ull     // bf16 [257][65536]  = 33685504  (write-once h slots)
#define FLG_OFF  63062016ull     // int  [257][256]    = 263168    (per-step per-block ready flags)
#define SLOT_BYTES 131072ull

__device__ __forceinline__ bf16x8 cvt8(float4 a, float4 b) {
  bf16x8 v;
  v[0] = (bf16_t)a.x; v[1] = (bf16_t)a.y; v[2] = (bf16_t)a.z; v[3] = (bf16_t)a.w;
  v[4] = (bf16_t)b.x; v[5] = (bf16_t)b.y; v[6] = (bf16_t)b.z; v[7] = (bf16_t)b.w;
  return v;
}

// ---------------- pack x -> bf16 MFMA A-fragment order ----------------
// xf elem(t, bg, kh, kkl, lane, e) = x[t][batch=bg*16+(lane&15)][k=(kh*8+kkl)*32+(lane>>4)*8+e]
__global__ __launch_bounds__(256) void pack_xf_k(const float* __restrict__ x,
                                                 bf16_t* __restrict__ xf) {
  int idx = blockIdx.x * 256 + threadIdx.x;     // 1,048,576 chunks of 8
  int t = idx >> 12;
  int r = idx & 4095;
  int batch = r >> 6, c8 = r & 63;
  const float4* s = (const float4*)(x + ((size_t)t * NBATCH + batch) * INDIM + c8 * 8);
  int kk = c8 >> 2, lhi = c8 & 3;
  int kh = kk >> 3, kkl = kk & 7;
  int bg = batch >> 4, lane = (batch & 15) + 16 * lhi;
  bf16_t* d = xf + (size_t)t * 32768 + (size_t)(((bg * 2 + kh) * 8 + kkl) * 64 + lane) * 8;
  *(bf16x8*)d = cvt8(s[0], s[1]);
}

// ---------------- pack weights (B-fragment order) + bias sums ----------------
struct GatePtrs {
  const float* Wi[4];
  const float* bi[4];
  const float* Wh[4];
  const float* bh[4];
};

__global__ __launch_bounds__(256) void pack_w_k(GatePtrs p,
                                                bf16_t* __restrict__ Wxf,
                                                bf16_t* __restrict__ Whf,
                                                float* __restrict__ bsum) {
  int idx = blockIdx.x * 256 + threadIdx.x;       // 0 .. 786431
  int row = idx / 192;                            // packed row, 0..4095
  int c   = idx % 192;
  int blk = row >> 5, r32 = row & 31, g = r32 >> 3, jj = r32 & 7;
  int j = blk * 8 + jj;                           // original hidden index
  int g2 = r32 >> 4, lrow = r32 & 15;
  if (c == 0) bsum[row] = p.bi[g][j] + p.bh[g][j];
  if (c < 64) {                                   // W_i row j, k-chunk c
    const float4* s = (const float4*)(p.Wi[g] + (size_t)j * INDIM + c * 8);
    int kk = c >> 2, lane = lrow + 16 * (c & 3);
    *(bf16x8*)(Wxf + (size_t)blk * 16384 + (size_t)((kk * 2 + g2) * 64 + lane) * 8) = cvt8(s[0], s[1]);
  } else {                                        // W_h row j, k-chunk cc
    int cc = c - 64;
    const float4* s = (const float4*)(p.Wh[g] + (size_t)j * HID + cc * 8);
    int kk = cc >> 2, lane = lrow + 16 * (cc & 3);
    *(bf16x8*)(Whf + (size_t)blk * 32768 + (size_t)((kk * 2 + g2) * 64 + lane) * 8) = cvt8(s[0], s[1]);
  }
}

// forced loads: PLDC = plain cacheable (L1/L2 path), flag poll uses sc0/sc1 (coherent)
#define PLDC(dst, ptr, OFF) \
  asm volatile("global_load_dwordx4 %0, %1, off offset:" OFF : "=v"(dst) : "v"(ptr))

// ---------------- persistent dataflow recurrence ----------------
// 256 blocks x 256 threads (4 waves, 1 block/CU forced by 105 KB LDS).
// Block b: cb = b&127 owns h cols [cb*8,+8) (32 gate-rows); bgs = b>>7 owns batches [32bgs,+32).
// Wave w: bhalf = w>>1 (16-batch half), kh = w&1 (K half); global bg = bgs*2+bhalf.
// Sync: producers publish h(t+1) (WT dword atomics) -> syncthreads (vmcnt drain: performed at
// IC) -> one flag dword per block. Consumers poll the 256-flag vector (sc0/sc1), then read h
// fragments with PLAIN CACHEABLE loads: slots are write-once, so the consumer XCD's L2 has
// never cached those lines -> the L2 fill from IC is fresh and SHARED by all 32 co-XCD blocks
// (IC data traffic ~16 MB/step -> ~1 MB/step). Weights in LDS (96 KB/block).
__global__ __launch_bounds__(256, 1) void lstm_rec_k(const bf16_t* __restrict__ Whf,
                                                     const bf16_t* __restrict__ Wxf,
                                                     const bf16_t* __restrict__ xf,
                                                     const float* __restrict__ bsum,
                                                     bf16_t* __restrict__ hseq,
                                                     int* __restrict__ flags,
                                                     float* __restrict__ out) {
  const int b = blockIdx.x;
  const int cb = b & 127, bgs = b >> 7;
  const int tid = threadIdx.x;
  const int w = tid >> 6, l = tid & 63;
  const int bhalf = w >> 1, kh = w & 1;
  const int bg = bgs * 2 + bhalf;

  __shared__ bf16_t wlds[49152];        // 96 KB: [0,32768) Whf slice, [32768,49152) Wxf slice
  __shared__ float  accbuf[2][32][36];  // 9 KB: [kh][gate-row][local batch32 + pad]

  // --- preload this col-block's weight fragments into LDS (coalesced DMA) ---
  {
    const bf16_t* whb = Whf + (size_t)cb * 32768;
    const bf16_t* wxb = Wxf + (size_t)cb * 16384;
#pragma unroll
    for (int i = 0; i < 16; ++i)
      __builtin_amdgcn_global_load_lds((const __attribute__((address_space(1))) void*)(whb + (i * 256 + tid) * 8),
                                       (__attribute__((address_space(3))) void*)(wlds + (i * 256 + tid) * 8),
                                       16, 0, 0);
#pragma unroll
    for (int i = 0; i < 8; ++i)
      __builtin_amdgcn_global_load_lds((const __attribute__((address_space(1))) void*)(wxb + (i * 256 + tid) * 8),
                                       (__attribute__((address_space(3))) void*)(wlds + 32768 + (i * 256 + tid) * 8),
                                       16, 0, 0);
  }

  // elementwise ownership: 1 cell/thread: local batch eb = tid>>3, col ejj = tid&7
  const int eb = tid >> 3, ejj = tid & 7;
  const int gb = bgs * 32 + eb;          // global batch
  const int j  = cb * 8 + ejj;           // h column
  // publish dword offset (even-j thread stores the pair {j, j+1})
  const int p_lane = (gb & 15) + 16 * ((j & 31) >> 3);
  const int p_kkg = j >> 5;
  const size_t pub_off = (size_t)((((gb >> 4) * 2 + (p_kkg >> 4)) * 16 + (p_kkg & 15)) * 64 + p_lane) * 16
                       + (size_t)(j & 7) * 2;
  const float bsF = bsum[cb * 32 + ejj];
  const float bsI = bsum[cb * 32 + 8 + ejj];
  const float bsO = bsum[cb * 32 + 16 + ejj];
  const float bsC = bsum[cb * 32 + 24 + ejj];
  float cs = 0.f;

  // per-wave fragment bases
  const size_t pollbase = (size_t)((bg * 2 + kh) * 16) * 1024 + (size_t)l * 16;  // bytes in slot
  const char* fbase = (const char*)flags + (size_t)l * 16;                        // + t*1024

  __syncthreads();   // weight LDS ready (barrier drains vmcnt)

  for (int t = 0; t < SEQLEN; ++t) {
    // x fragments: 8 plain forced loads, in flight across the flag poll
    const bf16_t* xfe = xf + (size_t)t * 32768 + (size_t)((bg * 2 + kh) * 8 * 64 + l) * 8;
    const char* xp0 = (const char*)xfe;
    const char* xp1 = xp0 + 4096;
    i32x4 xr[8];
    PLDC(xr[0], xp0, "0"); PLDC(xr[1], xp0, "1024"); PLDC(xr[2], xp0, "2048"); PLDC(xr[3], xp0, "3072");
    PLDC(xr[4], xp1, "0"); PLDC(xr[5], xp1, "1024"); PLDC(xr[6], xp1, "2048"); PLDC(xr[7], xp1, "3072");

    // ---- flag poll: 1 KB coherent vector, cheap retry ----
    if (t) {
      const char* fp = fbase + (size_t)t * 1024;
      i32x4 f;
      for (;;) {
        asm volatile("global_load_dwordx4 %0, %1, off sc0 sc1" : "=v"(f) : "v"(fp));
        asm volatile("s_waitcnt vmcnt(0)" ::: "memory");
        if (!__any((f[0] == 0) | (f[1] == 0) | (f[2] == 0) | (f[3] == 0))) break;
        __builtin_amdgcn_s_sleep(1);
      }
    }
    asm volatile("" ::: "memory");

    // ---- h fragments: 16 plain cacheable forced loads (L2-shared within XCD) ----
    const char* q0 = (const char*)hseq + (size_t)t * SLOT_BYTES + pollbase;
    const char* q1 = q0 + 4096;
    const char* q2 = q0 + 8192;
    const char* q3 = q0 + 12288;
    i32x4 hv[16];
    PLDC(hv[0],  q0, "0"); PLDC(hv[1],  q0, "1024"); PLDC(hv[2],  q0, "2048"); PLDC(hv[3],  q0, "3072");
    PLDC(hv[4],  q1, "0"); PLDC(hv[5],  q1, "1024"); PLDC(hv[6],  q1, "2048"); PLDC(hv[7],  q1, "3072");
    PLDC(hv[8],  q2, "0"); PLDC(hv[9],  q2, "1024"); PLDC(hv[10], q2, "2048"); PLDC(hv[11], q2, "3072");
    PLDC(hv[12], q3, "0"); PLDC(hv[13], q3, "1024"); PLDC(hv[14], q3, "2048"); PLDC(hv[15], q3, "3072");
    asm volatile("s_waitcnt vmcnt(0)" ::: "memory");
    __builtin_amdgcn_sched_barrier(0);

    // ---- MFMA: h (K=512 per wave) + x (K=256 per wave), B from LDS ----
    f32x4 acc0 = {}, acc1 = {};
#pragma unroll
    for (int kkl = 0; kkl < 16; ++kkl) {
      const int kk = kh * 16 + kkl;
      bf16x8 hf = __builtin_bit_cast(bf16x8, hv[kkl]);
      bf16x8 w0 = *(const bf16x8*)(wlds + (size_t)((kk * 2 + 0) * 64 + l) * 8);
      bf16x8 w1 = *(const bf16x8*)(wlds + (size_t)((kk * 2 + 1) * 64 + l) * 8);
      acc0 = __builtin_amdgcn_mfma_f32_16x16x32_bf16(hf, w0, acc0, 0, 0, 0);
      acc1 = __builtin_amdgcn_mfma_f32_16x16x32_bf16(hf, w1, acc1, 0, 0, 0);
    }
#pragma unroll
    for (int kkl = 0; kkl < 8; ++kkl) {
      const int kk = kh * 8 + kkl;
      bf16x8 xv = __builtin_bit_cast(bf16x8, xr[kkl]);
      bf16x8 w0 = *(const bf16x8*)(wlds + 32768 + (size_t)((kk * 2 + 0) * 64 + l) * 8);
      bf16x8 w1 = *(const bf16x8*)(wlds + 32768 + (size_t)((kk * 2 + 1) * 64 + l) * 8);
      acc0 = __builtin_amdgcn_mfma_f32_16x16x32_bf16(xv, w0, acc0, 0, 0, 0);
      acc1 = __builtin_amdgcn_mfma_f32_16x16x32_bf16(xv, w1, acc1, 0, 0, 0);
    }

    // D layout: gate-row = g2*16 + (l&15), local batch = bhalf*16 + (l>>4)*4 + reg
    *(f32x4*)&accbuf[kh][l & 15][bhalf * 16 + (l >> 4) * 4]        = acc0;
    *(f32x4*)&accbuf[kh][16 + (l & 15)][bhalf * 16 + (l >> 4) * 4] = acc1;
    __syncthreads();

    // ---- fused elementwise: 1 cell/thread ----
    {
      float pf = bsF + accbuf[0][ejj][eb]      + accbuf[1][ejj][eb];
      float pi = bsI + accbuf[0][8 + ejj][eb]  + accbuf[1][8 + ejj][eb];
      float po = bsO + accbuf[0][16 + ejj][eb] + accbuf[1][16 + ejj][eb];
      float pc = bsC + accbuf[0][24 + ejj][eb] + accbuf[1][24 + ejj][eb];
      float fg = 1.f / (1.f + __expf(-pf));
      float ig = 1.f / (1.f + __expf(-pi));
      float og = 1.f / (1.f + __expf(-po));
      float e2 = __expf(-2.f * fabsf(pc));
      float gg = __builtin_copysignf((1.f - e2) / (1.f + e2), pc);
      cs = fg * cs + ig * gg;
      float e2c = __expf(-2.f * fabsf(cs));
      float th = __builtin_copysignf((1.f - e2c) / (1.f + e2c), cs);
      float hval = og * th;

      out[((size_t)t * NBATCH + gb) * HID + j] = hval;
      // publish h(t+1): pair adjacent columns via shfl, even thread stores dword (WT, agent)
      unsigned int my = (unsigned int)__builtin_bit_cast(unsigned short, (bf16_t)hval);
      unsigned int other = __shfl_xor(my, 1);
      if (!(tid & 1)) {
        unsigned int pk = my | (other << 16);
        unsigned int* hd = (unsigned int*)((char*)hseq + (size_t)(t + 1) * SLOT_BYTES + pub_off);
        __hip_atomic_store(hd, pk, __ATOMIC_RELAXED, __HIP_MEMORY_SCOPE_AGENT);
      }
      if (t == SEQLEN - 1) {
        out[(size_t)SEQLEN * NBATCH * HID + (size_t)gb * HID + j] = hval;
        out[(size_t)SEQLEN * NBATCH * HID + (size_t)NBATCH * HID + (size_t)gb * HID + j] = cs;
      }
    }

    // ---- release: drain publishes, then one flag per block ----
    __syncthreads();   // per-wave vmcnt(0) drain: all WT h-stores performed at IC
    if (t < SEQLEN - 1 && tid == 0)
      __hip_atomic_store(&flags[(t + 1) * NBLK + b], 1, __ATOMIC_RELAXED, __HIP_MEMORY_SCOPE_AGENT);
  }
}

extern "C" void kernel_launch(void* const* d_in, const int* in_sizes, int n_in,
                              void* d_out, int out_size, void* d_ws, size_t ws_size,
                              hipStream_t stream) {
  (void)in_sizes; (void)n_in; (void)out_size; (void)ws_size;
  char* ws = (char*)d_ws;
  bf16_t* xf   = (bf16_t*)(ws + XF_OFF);
  bf16_t* Wxf  = (bf16_t*)(ws + WXF_OFF);
  bf16_t* Whf  = (bf16_t*)(ws + WHF_OFF);
  float*  bs   = (float*)(ws + BS_OFF);
  bf16_t* hseq = (bf16_t*)(ws + HSEQ_OFF);
  int*    flg  = (int*)(ws + FLG_OFF);

  const float* x = (const float*)d_in[0];
  GatePtrs p;
  for (int g = 0; g < 4; ++g) {
    p.Wi[g] = (const float*)d_in[1 + 4 * g];
    p.bi[g] = (const float*)d_in[2 + 4 * g];
    p.Wh[g] = (const float*)d_in[3 + 4 * g];
    p.bh[g] = (const float*)d_in[4 + 4 * g];
  }

  pack_xf_k<<<4096, 256, 0, stream>>>(x, xf);
  pack_w_k<<<3072, 256, 0, stream>>>(p, Wxf, Whf, bs);
  hipMemsetAsync(flg, 0, 257 * NBLK * 4, stream);
  hipMemsetAsync(hseq, 0, SLOT_BYTES, stream);   // slot 0 = h(0) = zeros
  lstm_rec_k<<<NBLK, 256, 0, stream>>>(Whf, Wxf, xf, bs, hseq, flg, (float*)d_out);
}

// Round 9
// 736.787 us; speedup vs baseline: 4.4462x; 1.1698x over previous
//
#include <hip/hip_runtime.h>
#include <hip/hip_bf16.h>

typedef __bf16 bf16_t;
typedef __bf16 bf16x8 __attribute__((ext_vector_type(8)));
typedef float f32x4 __attribute__((ext_vector_type(4)));
typedef int   i32x4 __attribute__((ext_vector_type(4)));

#define SEQLEN 256
#define NBATCH 64
#define INDIM  512
#define HID    1024
#define NBLK   256

// workspace layout (bytes) — total ~63.3 MB
#define XF_OFF   0ull            // bf16 [256][32768]  = 16777216  (x fragments)
#define WXF_OFF  16777216ull     // bf16 [128][16384]  = 4194304   (W_i fragments per col-block)
#define WHF_OFF  20971520ull     // bf16 [128][32768]  = 8388608   (W_h fragments per col-block)
#define BS_OFF   29360128ull     // f32  [4096]        = 16384     (bias sums)
#define HSEQ_OFF 29376512ull     // bf16 [257][65536]  = 33685504  (write-once h slots)
#define FLG_OFF  63062016ull     // int  [257][256]    = 263168    (per-step per-block ready flags)
#define SLOT_BYTES 131072ull

__device__ __forceinline__ bf16x8 cvt8(float4 a, float4 b) {
  bf16x8 v;
  v[0] = (bf16_t)a.x; v[1] = (bf16_t)a.y; v[2] = (bf16_t)a.z; v[3] = (bf16_t)a.w;
  v[4] = (bf16_t)b.x; v[5] = (bf16_t)b.y; v[6] = (bf16_t)b.z; v[7] = (bf16_t)b.w;
  return v;
}

// ---------------- pack x -> bf16 MFMA A-fragment order ----------------
__global__ __launch_bounds__(256) void pack_xf_k(const float* __restrict__ x,
                                                 bf16_t* __restrict__ xf) {
  int idx = blockIdx.x * 256 + threadIdx.x;     // 1,048,576 chunks of 8
  int t = idx >> 12;
  int r = idx & 4095;
  int batch = r >> 6, c8 = r & 63;
  const float4* s = (const float4*)(x + ((size_t)t * NBATCH + batch) * INDIM + c8 * 8);
  int kk = c8 >> 2, lhi = c8 & 3;
  int kh = kk >> 3, kkl = kk & 7;
  int bg = batch >> 4, lane = (batch & 15) + 16 * lhi;
  bf16_t* d = xf + (size_t)t * 32768 + (size_t)(((bg * 2 + kh) * 8 + kkl) * 64 + lane) * 8;
  *(bf16x8*)d = cvt8(s[0], s[1]);
}

// ---------------- pack weights (B-fragment order) + bias sums ----------------
struct GatePtrs {
  const float* Wi[4];
  const float* bi[4];
  const float* Wh[4];
  const float* bh[4];
};

__global__ __launch_bounds__(256) void pack_w_k(GatePtrs p,
                                                bf16_t* __restrict__ Wxf,
                                                bf16_t* __restrict__ Whf,
                                                float* __restrict__ bsum) {
  int idx = blockIdx.x * 256 + threadIdx.x;       // 0 .. 786431
  int row = idx / 192;                            // packed row, 0..4095
  int c   = idx % 192;
  int blk = row >> 5, r32 = row & 31, g = r32 >> 3, jj = r32 & 7;
  int j = blk * 8 + jj;                           // original hidden index
  int g2 = r32 >> 4, lrow = r32 & 15;
  if (c == 0) bsum[row] = p.bi[g][j] + p.bh[g][j];
  if (c < 64) {                                   // W_i row j, k-chunk c
    const float4* s = (const float4*)(p.Wi[g] + (size_t)j * INDIM + c * 8);
    int kk = c >> 2, lane = lrow + 16 * (c & 3);
    *(bf16x8*)(Wxf + (size_t)blk * 16384 + (size_t)((kk * 2 + g2) * 64 + lane) * 8) = cvt8(s[0], s[1]);
  } else {                                        // W_h row j, k-chunk cc
    int cc = c - 64;
    const float4* s = (const float4*)(p.Wh[g] + (size_t)j * HID + cc * 8);
    int kk = cc >> 2, lane = lrow + 16 * (cc & 3);
    *(bf16x8*)(Whf + (size_t)blk * 32768 + (size_t)((kk * 2 + g2) * 64 + lane) * 8) = cvt8(s[0], s[1]);
  }
}

// forced plain-cacheable loads (issue pinned by asm; completion via explicit s_waitcnt)
#define PLDC(dst, ptr, OFF) \
  asm volatile("global_load_dwordx4 %0, %1, off offset:" OFF : "=v"(dst) : "v"(ptr))

// ---------------- persistent dataflow recurrence ----------------
// 256 blocks x 256 threads (4 waves), 1 block/CU (LDS pad + VGPR pressure).
// Block b: cb = b&127 owns h cols [cb*8,+8); bgs = b>>7 owns batches [32bgs,+32).
// Wave w: bhalf = w>>1, kh = w&1; global bg = bgs*2+bhalf.
// W_h fragments live in VGPRs (128/lane, loaded once via asm); W_i fragments in LDS.
// Per step: issue x loads -> poll flags -> issue h loads -> x-part MFMA in the h-load
// shadow (vmcnt(16) = xr retired, in-order) -> vmcnt(0) -> h-part reg-only MFMA ->
// accbuf reduce -> elementwise -> publish (WT dword atomics) -> drain -> flag.
__global__ __launch_bounds__(256, 1) void lstm_rec_k(const bf16_t* __restrict__ Whf,
                                                     const bf16_t* __restrict__ Wxf,
                                                     const bf16_t* __restrict__ xf,
                                                     const float* __restrict__ bsum,
                                                     bf16_t* __restrict__ hseq,
                                                     int* __restrict__ flags,
                                                     float* __restrict__ out) {
  const int b = blockIdx.x;
  const int cb = b & 127, bgs = b >> 7;
  const int tid = threadIdx.x;
  const int w = tid >> 6, l = tid & 63;
  const int bhalf = w >> 1, kh = w & 1;
  const int bg = bgs * 2 + bhalf;

  __shared__ bf16_t xwlds[16384];       // 32 KB: W_i fragments
  __shared__ float  accbuf[2][32][36];  // 9 KB: [kh][gate-row][local batch32 + pad]
  __shared__ char   ldspad[45056];      // pin 1 block/CU

  if (tid > 1000000) ((volatile char*)ldspad)[0] = 1;   // keep pad allocated

  // --- W_i fragments -> LDS (coalesced DMA) ---
#pragma unroll
  for (int i = 0; i < 8; ++i)
    __builtin_amdgcn_global_load_lds((const __attribute__((address_space(1))) void*)(Wxf + (size_t)cb * 16384 + (i * 256 + tid) * 8),
                                     (__attribute__((address_space(3))) void*)(xwlds + (i * 256 + tid) * 8),
                                     16, 0, 0);

  // --- W_h fragments -> VGPRs (32 x dwordx4 asm loads, loop-invariant) ---
  i32x4 whr[16][2];
  {
    const char* wb = (const char*)Whf + (size_t)cb * 65536 + (size_t)(kh * 32768) + (size_t)l * 16;
    const char* w0 = wb;          const char* w1 = wb + 4096;
    const char* w2 = wb + 8192;   const char* w3 = wb + 12288;
    const char* w4 = wb + 16384;  const char* w5 = wb + 20480;
    const char* w6 = wb + 24576;  const char* w7 = wb + 28672;
    PLDC(whr[0][0],  w0, "0"); PLDC(whr[0][1],  w0, "1024"); PLDC(whr[1][0],  w0, "2048"); PLDC(whr[1][1],  w0, "3072");
    PLDC(whr[2][0],  w1, "0"); PLDC(whr[2][1],  w1, "1024"); PLDC(whr[3][0],  w1, "2048"); PLDC(whr[3][1],  w1, "3072");
    PLDC(whr[4][0],  w2, "0"); PLDC(whr[4][1],  w2, "1024"); PLDC(whr[5][0],  w2, "2048"); PLDC(whr[5][1],  w2, "3072");
    PLDC(whr[6][0],  w3, "0"); PLDC(whr[6][1],  w3, "1024"); PLDC(whr[7][0],  w3, "2048"); PLDC(whr[7][1],  w3, "3072");
    PLDC(whr[8][0],  w4, "0"); PLDC(whr[8][1],  w4, "1024"); PLDC(whr[9][0],  w4, "2048"); PLDC(whr[9][1],  w4, "3072");
    PLDC(whr[10][0], w5, "0"); PLDC(whr[10][1], w5, "1024"); PLDC(whr[11][0], w5, "2048"); PLDC(whr[11][1], w5, "3072");
    PLDC(whr[12][0], w6, "0"); PLDC(whr[12][1], w6, "1024"); PLDC(whr[13][0], w6, "2048"); PLDC(whr[13][1], w6, "3072");
    PLDC(whr[14][0], w7, "0"); PLDC(whr[14][1], w7, "1024"); PLDC(whr[15][0], w7, "2048"); PLDC(whr[15][1], w7, "3072");
  }
  asm volatile("s_waitcnt vmcnt(0)" ::: "memory");
  __builtin_amdgcn_sched_barrier(0);

  // elementwise ownership: local batch eb = tid>>3, col ejj = tid&7
  const int eb = tid >> 3, ejj = tid & 7;
  const int gb = bgs * 32 + eb;
  const int j  = cb * 8 + ejj;
  const int p_lane = (gb & 15) + 16 * ((j & 31) >> 3);
  const int p_kkg = j >> 5;
  const size_t pub_off = (size_t)((((gb >> 4) * 2 + (p_kkg >> 4)) * 16 + (p_kkg & 15)) * 64 + p_lane) * 16
                       + (size_t)(j & 7) * 2;
  const float bsF = bsum[cb * 32 + ejj];
  const float bsI = bsum[cb * 32 + 8 + ejj];
  const float bsO = bsum[cb * 32 + 16 + ejj];
  const float bsC = bsum[cb * 32 + 24 + ejj];
  float cs = 0.f;

  const size_t pollbase = (size_t)((bg * 2 + kh) * 16) * 1024 + (size_t)l * 16;
  const char* fbase = (const char*)flags + (size_t)l * 16;

  __syncthreads();   // xwlds DMA complete

  for (int t = 0; t < SEQLEN; ++t) {
    // ---- 1. x fragments: 8 forced loads, in flight across the poll ----
    const char* xp0 = (const char*)xf + (size_t)t * 65536 + (size_t)((bg * 2 + kh) * 8 * 64 + l) * 16;
    const char* xp1 = xp0 + 4096;
    i32x4 xr[8];
    PLDC(xr[0], xp0, "0"); PLDC(xr[1], xp0, "1024"); PLDC(xr[2], xp0, "2048"); PLDC(xr[3], xp0, "3072");
    PLDC(xr[4], xp1, "0"); PLDC(xr[5], xp1, "1024"); PLDC(xr[6], xp1, "2048"); PLDC(xr[7], xp1, "3072");

    // ---- 2. flag poll (sc0/sc1 coherent vector) ----
    if (t) {
      const char* fp = fbase + (size_t)t * 1024;
      i32x4 f;
      for (;;) {
        asm volatile("global_load_dwordx4 %0, %1, off sc0 sc1" : "=v"(f) : "v"(fp));
        asm volatile("s_waitcnt vmcnt(0)" ::: "memory");
        if (!__any((f[0] == 0) | (f[1] == 0) | (f[2] == 0) | (f[3] == 0))) break;
        __builtin_amdgcn_s_sleep(1);
      }
    }
    asm volatile("" ::: "memory");

    // ---- 3. issue h fragment loads (plain cacheable; L2-shared within XCD) ----
    const char* q0 = (const char*)hseq + (size_t)t * SLOT_BYTES + pollbase;
    const char* q1 = q0 + 4096;
    const char* q2 = q0 + 8192;
    const char* q3 = q0 + 12288;
    i32x4 hv[16];
    PLDC(hv[0],  q0, "0"); PLDC(hv[1],  q0, "1024"); PLDC(hv[2],  q0, "2048"); PLDC(hv[3],  q0, "3072");
    PLDC(hv[4],  q1, "0"); PLDC(hv[5],  q1, "1024"); PLDC(hv[6],  q1, "2048"); PLDC(hv[7],  q1, "3072");
    PLDC(hv[8],  q2, "0"); PLDC(hv[9],  q2, "1024"); PLDC(hv[10], q2, "2048"); PLDC(hv[11], q2, "3072");
    PLDC(hv[12], q3, "0"); PLDC(hv[13], q3, "1024"); PLDC(hv[14], q3, "2048"); PLDC(hv[15], q3, "3072");

    // ---- 4. x-part MFMA in the h-load shadow (vmcnt in-order: 16 left = xr retired) ----
    asm volatile("s_waitcnt vmcnt(16)" ::: "memory");
    __builtin_amdgcn_sched_barrier(0);
    f32x4 acc0 = {}, acc1 = {};
#pragma unroll
    for (int kkl = 0; kkl < 8; ++kkl) {
      const int kk = kh * 8 + kkl;
      bf16x8 xv = __builtin_bit_cast(bf16x8, xr[kkl]);
      bf16x8 w0 = *(const bf16x8*)(xwlds + (size_t)((kk * 2 + 0) * 64 + l) * 8);
      bf16x8 w1 = *(const bf16x8*)(xwlds + (size_t)((kk * 2 + 1) * 64 + l) * 8);
      acc0 = __builtin_amdgcn_mfma_f32_16x16x32_bf16(xv, w0, acc0, 0, 0, 0);
      acc1 = __builtin_amdgcn_mfma_f32_16x16x32_bf16(xv, w1, acc1, 0, 0, 0);
    }

    // ---- 5. h-part: reg-only MFMA (weights in VGPRs) ----
    asm volatile("s_waitcnt vmcnt(0)" ::: "memory");
    __builtin_amdgcn_sched_barrier(0);
#pragma unroll
    for (int kkl = 0; kkl < 16; ++kkl) {
      bf16x8 hf = __builtin_bit_cast(bf16x8, hv[kkl]);
      acc0 = __builtin_amdgcn_mfma_f32_16x16x32_bf16(hf, __builtin_bit_cast(bf16x8, whr[kkl][0]), acc0, 0, 0, 0);
      acc1 = __builtin_amdgcn_mfma_f32_16x16x32_bf16(hf, __builtin_bit_cast(bf16x8, whr[kkl][1]), acc1, 0, 0, 0);
    }

    // D layout: gate-row = g2*16 + (l&15), local batch = bhalf*16 + (l>>4)*4 + reg
    *(f32x4*)&accbuf[kh][l & 15][bhalf * 16 + (l >> 4) * 4]        = acc0;
    *(f32x4*)&accbuf[kh][16 + (l & 15)][bhalf * 16 + (l >> 4) * 4] = acc1;
    __syncthreads();

    // ---- 6. fused elementwise: 1 cell/thread ----
    float hval;
    {
      float pf = bsF + accbuf[0][ejj][eb]      + accbuf[1][ejj][eb];
      float pi = bsI + accbuf[0][8 + ejj][eb]  + accbuf[1][8 + ejj][eb];
      float po = bsO + accbuf[0][16 + ejj][eb] + accbuf[1][16 + ejj][eb];
      float pc = bsC + accbuf[0][24 + ejj][eb] + accbuf[1][24 + ejj][eb];
      float fg = 1.f / (1.f + __expf(-pf));
      float ig = 1.f / (1.f + __expf(-pi));
      float og = 1.f / (1.f + __expf(-po));
      float e2 = __expf(-2.f * fabsf(pc));
      float gg = __builtin_copysignf((1.f - e2) / (1.f + e2), pc);
      cs = fg * cs + ig * gg;
      float e2c = __expf(-2.f * fabsf(cs));
      float th = __builtin_copysignf((1.f - e2c) / (1.f + e2c), cs);
      hval = og * th;

      // publish h(t+1) first (it gates the chain); out-stores follow the flag
      unsigned int my = (unsigned int)__builtin_bit_cast(unsigned short, (bf16_t)hval);
      unsigned int other = __shfl_xor(my, 1);
      if (!(tid & 1)) {
        unsigned int pk = my | (other << 16);
        unsigned int* hd = (unsigned int*)((char*)hseq + (size_t)(t + 1) * SLOT_BYTES + pub_off);
        __hip_atomic_store(hd, pk, __ATOMIC_RELAXED, __HIP_MEMORY_SCOPE_AGENT);
      }
    }

    // ---- 7. release: drain publishes, one flag per block, then background stores ----
    __syncthreads();   // per-wave vmcnt(0) drain: h-stores performed at IC
    if (t < SEQLEN - 1 && tid == 0)
      __hip_atomic_store(&flags[(t + 1) * NBLK + b], 1, __ATOMIC_RELAXED, __HIP_MEMORY_SCOPE_AGENT);

    out[((size_t)t * NBATCH + gb) * HID + j] = hval;
    if (t == SEQLEN - 1) {
      out[(size_t)SEQLEN * NBATCH * HID + (size_t)gb * HID + j] = hval;
      out[(size_t)SEQLEN * NBATCH * HID + (size_t)NBATCH * HID + (size_t)gb * HID + j] = cs;
    }
  }
}

extern "C" void kernel_launch(void* const* d_in, const int* in_sizes, int n_in,
                              void* d_out, int out_size, void* d_ws, size_t ws_size,
                              hipStream_t stream) {
  (void)in_sizes; (void)n_in; (void)out_size; (void)ws_size;
  char* ws = (char*)d_ws;
  bf16_t* xf   = (bf16_t*)(ws + XF_OFF);
  bf16_t* Wxf  = (bf16_t*)(ws + WXF_OFF);
  bf16_t* Whf  = (bf16_t*)(ws + WHF_OFF);
  float*  bs   = (float*)(ws + BS_OFF);
  bf16_t* hseq = (bf16_t*)(ws + HSEQ_OFF);
  int*    flg  = (int*)(ws + FLG_OFF);

  const float* x = (const float*)d_in[0];
  GatePtrs p;
  for (int g = 0; g < 4; ++g) {
    p.Wi[g] = (const float*)d_in[1 + 4 * g];
    p.bi[g] = (const float*)d_in[2 + 4 * g];
    p.Wh[g] = (const float*)d_in[3 + 4 * g];
    p.bh[g] = (const float*)d_in[4 + 4 * g];
  }

  pack_xf_k<<<4096, 256, 0, stream>>>(x, xf);
  pack_w_k<<<3072, 256, 0, stream>>>(p, Wxf, Whf, bs);
  hipMemsetAsync(flg, 0, 257 * NBLK * 4, stream);
  hipMemsetAsync(hseq, 0, SLOT_BYTES, stream);   // slot 0 = h(0) = zeros
  lstm_rec_k<<<NBLK, 256, 0, stream>>>(Whf, Wxf, xf, bs, hseq, flg, (float*)d_out);
}